// Round 18
// baseline (946.980 us; speedup 1.0000x reference)
//
#include <hip/hip_runtime.h>

typedef unsigned int u32;
typedef _Float16 f16;
typedef __attribute__((ext_vector_type(8))) _Float16 f16x8;
typedef __attribute__((ext_vector_type(4))) _Float16 f16x4;
typedef __attribute__((ext_vector_type(4))) float f32x4;

#define NNODES 100000
#define NEDGES 600000
#define CC 16
#define HH 48
#define NL 5
#define ECT 5                      // tiles of 64 edges per ec block
#define ECNB 1875                  // 1875 * 5 * 64 = 600000 exact

// ---- ws layout (float units), total 4,000,064 floats = 16.0 MB ----
// agg [1.6M,3.2M) is transient (both NCs); actp/outp alias inside it afterwards.
#define OX1   0                    // xh1 f16 (1.6M halfs = 800k floats)
#define OX2   800000               // xh2 f16
#define OAGG  1600000              // agg fp32 1.6M floats [1.6M, 3.2M)
#define OACTP 1600000              // actp (after agg dead)
#define OOUTP 2200000              // outp (after agg dead)
#define OROW  3200000
#define ODEG  3300032              // deg during CSR build; then gf (f16 39936)
#define OGF   3300032
#define OPERM 3400032
#define OSL   4000032
#define WS_NEED_FLOATS 4000064

// =================== CSR build ===================
__global__ __launch_bounds__(256) void count_deg(const int* __restrict__ ei, int* __restrict__ deg){
  int e = blockIdx.x * 256 + threadIdx.x;
  if (e >= NEDGES) return;
  atomicAdd(&deg[ei[NEDGES + e]], 1);
}

__global__ __launch_bounds__(1024) void scan_deg(const int* __restrict__ deg, int* __restrict__ rowptr){
  __shared__ int part[1024];
  int t = threadIdx.x;
  const int CH = (NNODES + 1023) / 1024;
  int b = t * CH;
  int e = b + CH < NNODES ? b + CH : NNODES;
  int s = 0;
  for (int i = b; i < e; i++) s += deg[i];
  part[t] = s;
  __syncthreads();
  for (int off = 1; off < 1024; off <<= 1){
    int v = (t >= off) ? part[t - off] : 0;
    __syncthreads();
    part[t] += v;
    __syncthreads();
  }
  int run = (t == 0) ? 0 : part[t - 1];
  for (int i = b; i < e; i++){ rowptr[i] = run; run += deg[i]; }
  if (t == 1023) rowptr[NNODES] = run;
}

__global__ __launch_bounds__(256) void scatter_perm(const int* __restrict__ ei,
    const int* __restrict__ rowptr, int* __restrict__ deg2, int* __restrict__ perm){
  int e = blockIdx.x * 256 + threadIdx.x;
  if (e >= NEDGES) return;
  int d = ei[NEDGES + e];
  int pos = rowptr[d] + atomicAdd(&deg2[d], 1);
  perm[pos] = e;
}

// =================== act pre-gather / out scatter (streaming) ===================
__global__ __launch_bounds__(256) void gather_act(const float* __restrict__ act,
    const int* __restrict__ perm, float* __restrict__ actp){
  int i = blockIdx.x * 256 + threadIdx.x;
  if (i >= NEDGES) return;
  actp[i] = act[perm[i]];
}

__global__ __launch_bounds__(256) void scatter_out(const float* __restrict__ outp,
    const int* __restrict__ perm, float* __restrict__ out){
  int i = blockIdx.x * 256 + threadIdx.x;
  if (i >= NEDGES) return;
  out[perm[i]] = outp[i];
}

// ============ W-fragment precompute (r13-proven) ============
__global__ __launch_bounds__(256) void prep_wfrag(
    const float* __restrict__ e1w0, const float* __restrict__ e1wh, const float* __restrict__ e1wc,
    const float* __restrict__ e2w0, const float* __restrict__ e2wh, f16* __restrict__ gf)
{
  int idx = blockIdx.x * 256 + threadIdx.x;
  if (idx >= 39936) return;
  int j = idx & 7, lane = (idx >> 3) & 63, f = idx >> 9;
  int wt = f % 3, ksl = f / 3;
  int ks = ksl & 1, lay = ksl >> 1;
  int k = ks * 32 + ((lane >> 4) << 3) + j;
  int m = wt * 16 + (lane & 15);
  const float* w; int Kl;
  if (lay == 0){ w = e1w0; Kl = 32; }
  else if (lay <= 5){ w = e1wh + (lay - 1) * 2304; Kl = 48; }
  else if (lay == 6){ w = e1wc; Kl = 48; }
  else if (lay == 7){ w = e2w0; Kl = 32; }
  else { w = e2wh + (lay - 8) * 2304; Kl = 48; }
  gf[idx] = (k < Kl) ? (f16)w[k * 48 + m] : (f16)0.f;
}

// ============================================================================
// NodeConv, edge-parallel in perm (dst-sorted) order. One thread per edge:
// full 33->16 MLP, then wave-level SEGMENTED suffix reduction over dst runs
// (6 masked shfl_down per channel); only run-head lanes issue atomics.
// ~12 heads/wave -> ~1.8M atomics total (vs 9.6M in r7). Mean fold in finalize.
// ============================================================================
template<bool F16IN>
__global__ __launch_bounds__(256) void nc_edge(
    const void* __restrict__ xin, const int* __restrict__ ei,
    const float* __restrict__ ang, const int* __restrict__ perm,
    const float* __restrict__ w0, const float* __restrict__ b0,
    const float* __restrict__ wh, const float* __restrict__ bh,
    float* __restrict__ agg)
{
  int i = blockIdx.x * 256 + threadIdx.x;
  const int lane = threadIdx.x & 63;
  bool valid = i < NEDGES;
  int i0 = valid ? i : (NEDGES - 1);
  int e = perm[i0];                       // coalesced (perm order)
  int s = ei[e], d = ei[NEDGES + e];

  float in[33];
  if (F16IN){
    const f16* xh = (const f16*)xin;
    f16x8 r0 = *(const f16x8*)&xh[(long)d * 16];
    f16x8 r1 = *(const f16x8*)&xh[(long)d * 16 + 8];
    f16x8 r2 = *(const f16x8*)&xh[(long)s * 16];
    f16x8 r3 = *(const f16x8*)&xh[(long)s * 16 + 8];
    #pragma unroll
    for (int k = 0; k < 8; k++){
      in[k] = (float)r0[k]; in[8+k] = (float)r1[k];
      in[16+k] = (float)r2[k]; in[24+k] = (float)r3[k];
    }
  } else {
    const float* xf = (const float*)xin;
    const float4* pd = (const float4*)(xf + (long)d * 16);
    const float4* ps = (const float4*)(xf + (long)s * 16);
    #pragma unroll
    for (int k = 0; k < 4; k++){
      float4 v = pd[k]; in[4*k]=v.x; in[4*k+1]=v.y; in[4*k+2]=v.z; in[4*k+3]=v.w;
    }
    #pragma unroll
    for (int k = 0; k < 4; k++){
      float4 v = ps[k]; in[16+4*k]=v.x; in[16+4*k+1]=v.y; in[16+4*k+2]=v.z; in[16+4*k+3]=v.w;
    }
  }
  in[32] = ang[e];

  float h[16], acc[16];
  #pragma unroll
  for (int j = 0; j < 16; j++) acc[j] = b0[j];
  #pragma unroll
  for (int k = 0; k < 33; k++){
    float v = in[k];
    #pragma unroll
    for (int j = 0; j < 16; j++) acc[j] = fmaf(v, w0[k*16 + j], acc[j]);
  }
  #pragma unroll
  for (int j = 0; j < 16; j++) h[j] = fmaxf(acc[j], 0.f);

  for (int l = 0; l < NL; l++){
    const float* w = wh + l * 256;
    const float* b = bh + l * 16;
    #pragma unroll
    for (int j = 0; j < 16; j++) acc[j] = b[j];
    #pragma unroll
    for (int k = 0; k < 16; k++){
      float v = h[k];
      #pragma unroll
      for (int j = 0; j < 16; j++) acc[j] = fmaf(v, w[k*16 + j], acc[j]);
    }
    #pragma unroll
    for (int j = 0; j < 16; j++) h[j] = fmaxf(acc[j], 0.f);
  }

  // ---- segmented suffix reduction over dst runs (dst sorted within wave) ----
  int dk = valid ? d : -1;                 // isolate tail lanes
  bool sm[6];
  {
    int o = 1;
    #pragma unroll
    for (int k2 = 0; k2 < 6; k2++, o <<= 1){
      int dn = __shfl_down(dk, o);
      sm[k2] = ((lane + o) < 64) && (dn == dk);
    }
  }
  int dprev = __shfl_up(dk, 1);
  bool head = valid && ((lane == 0) || (dprev != dk));
  float* ag = agg + (long)d * 16;
  #pragma unroll
  for (int ch = 0; ch < 16; ch++){
    float v = valid ? h[ch] : 0.f;
    int o = 1;
    #pragma unroll
    for (int k2 = 0; k2 < 6; k2++, o <<= 1){
      float vn = __shfl_down(v, o);
      if (sm[k2]) v += vn;
    }
    if (head) atomicAdd(ag + ch, v);
  }
}

// ---- finalize: xh[n] = f16( agg[n] / max(deg,1) ), deg from rowptr ----
__global__ __launch_bounds__(256) void node_finh(
    const float* __restrict__ agg, const int* __restrict__ rowptr, f16* __restrict__ xh)
{
  int n = blockIdx.x * 256 + threadIdx.x;
  if (n >= NNODES) return;
  float inv = 1.f / fmaxf((float)(rowptr[n+1] - rowptr[n]), 1.f);
  const float4* ap = (const float4*)&agg[(long)n * 16];
  f16x8 o0, o1;
  #pragma unroll
  for (int k = 0; k < 2; k++){
    float4 v = ap[k];
    o0[4*k] = (f16)(v.x*inv); o0[4*k+1] = (f16)(v.y*inv);
    o0[4*k+2] = (f16)(v.z*inv); o0[4*k+3] = (f16)(v.w*inv);
  }
  #pragma unroll
  for (int k = 0; k < 2; k++){
    float4 v = ap[2+k];
    o1[4*k] = (f16)(v.x*inv); o1[4*k+1] = (f16)(v.y*inv);
    o1[4*k+2] = (f16)(v.z*inv); o1[4*k+3] = (f16)(v.w*inv);
  }
  *(f16x8*)&xh[(long)n * 16]     = o0;
  *(f16x8*)&xh[(long)n * 16 + 8] = o1;
}

// ============================================================================
// Fused EdgeConv1+EdgeConv2 v5 (r15/r17-proven) with wc* register trim:
// combine weights loaded inside modes 2/3 (frees ~36 persistent VGPRs).
// ============================================================================
__global__ __launch_bounds__(256) void ec_mfma(
    const f16* __restrict__ xh1, const f16* __restrict__ xh2,
    const int* __restrict__ ei, const int* __restrict__ perm,
    const float* __restrict__ actp, const f16* __restrict__ gf,
    const float* __restrict__ e1wc, const float* __restrict__ e1b0,
    const float* __restrict__ e1bh, const float* __restrict__ e1bc,
    const float* __restrict__ e2b0, const float* __restrict__ e2bh,
    const float* __restrict__ e2wc, const float* __restrict__ e2bc,
    float* __restrict__ outp, float* __restrict__ slacc)
{
  __shared__ __align__(16) f16 Hb[2][128 * 64];   // 32768 B

  const int t = threadIdx.x;
  const int lane = t & 63;
  const int wv = t >> 6;
  const int q = lane >> 4, n15 = lane & 15;
  const int row = t >> 1, half = t & 1;
  const int gebase = blockIdx.x * (ECT * 64);

  // ---- prologue: node ids for all tiles (this thread stages row `row`) ----
  int node[ECT];
  #pragma unroll
  for (int tt = 0; tt < ECT; tt++){
    int pe = perm[gebase + tt * 64 + (row & 63)];
    int s = ei[pe], dn = ei[NEDGES + pe];
    node[tt] = ((half ^ (row >> 6)) & 1) ? s : dn;   // f1=[x_d|x_s], f2=[x_s|x_d]
  }

  f16x8 pa0, pa1;                  // prefetched H data for the upcoming step
  const int rs = row & 7;
  auto store_lds = [&](f16* H){
    f16* hp = &H[row << 6];
    *(f16x8*)&hp[((2*half)     ^ rs) << 3] = pa0;
    *(f16x8*)&hp[((2*half + 1) ^ rs) << 3] = pa1;
    if (half){
      f16x8 z = {};
      *(f16x8*)&hp[(6 ^ rs) << 3] = z;
      *(f16x8*)&hp[(7 ^ rs) << 3] = z;
    }
  };

  float ef[3][4];
  float side = 0.f;
  float outAcc = 0.f;
  float aL = 0.f;

  auto layer = [&](f16* H, int lay, const float* bias, int nks, int mode){
    const int nEt = (mode == 2) ? 1 : 2;
    f32x4 C[3][2];
    #pragma unroll
    for (int wt = 0; wt < 3; wt++){
      float4 b4 = *(const float4*)&bias[wt*16 + 4*q];
      C[wt][0] = (f32x4){b4.x, b4.y, b4.z, b4.w};
      C[wt][1] = C[wt][0];
    }
    for (int ks = 0; ks < nks; ks++){
      int c = ks*4 + q;
      f16x8 Af[3];
      #pragma unroll
      for (int wt = 0; wt < 3; wt++)
        Af[wt] = *(const f16x8*)&gf[((((lay*2 + ks)*3) + wt) << 9) + (lane << 3)];
      for (int et = 0; et < nEt; et++){
        int r = (et << 6) + wv*16 + n15;
        f16x8 Bf = *(const f16x8*)&H[(r << 6) + ((c ^ (r & 7)) << 3)];
        #pragma unroll
        for (int wt = 0; wt < 3; wt++)
          C[wt][et] = __builtin_amdgcn_mfma_f32_16x16x32_f16(Af[wt], Bf, C[wt][et], 0, 0, 0);
      }
    }
    if (mode == 0){
      #pragma unroll
      for (int et = 0; et < 2; et++){
        int r = (et << 6) + wv*16 + n15;
        #pragma unroll
        for (int wt = 0; wt < 3; wt++){
          f16x4 pk;
          #pragma unroll
          for (int reg = 0; reg < 4; reg++) pk[reg] = (f16)fmaxf(C[wt][et][reg], 0.f);
          int col = wt*16 + 4*q;
          *(f16x4*)&H[(r << 6) + ((((col >> 3) ^ (r & 7)) << 3) | (col & 7))] = pk;
        }
      }
    } else if (mode == 1){
      int r = wv*16 + n15;
      #pragma unroll
      for (int wt = 0; wt < 3; wt++){
        f16x4 pk;
        #pragma unroll
        for (int reg = 0; reg < 4; reg++){
          float v1 = fmaxf(C[wt][0][reg], 0.f);
          float v2 = fmaxf(C[wt][1][reg], 0.f);
          float dd = v1 - v2; side += dd * dd;
          pk[reg] = (f16)(0.5f * (v1 + v2));
        }
        int col = wt*16 + 4*q;
        *(f16x4*)&H[(r << 6) + ((((col >> 3) ^ (r & 7)) << 3) | (col & 7))] = pk;
      }
    } else if (mode == 2){
      #pragma unroll
      for (int wt = 0; wt < 3; wt++){
        float4 wr = *(const float4*)&e1wc[2304 + wt*16 + 4*q];  // wc1 action row 48
        ef[wt][0] = C[wt][0][0] + aL * wr.x;
        ef[wt][1] = C[wt][0][1] + aL * wr.y;
        ef[wt][2] = C[wt][0][2] + aL * wr.z;
        ef[wt][3] = C[wt][0][3] + aL * wr.w;
      }
    } else {
      #pragma unroll
      for (int wt = 0; wt < 3; wt++){
        float4 wa = *(const float4*)&e2wc[wt*16 + 4*q];         // wc2[0:48]
        float4 wb = *(const float4*)&e2wc[48 + wt*16 + 4*q];    // wc2[48:96]
        float av[4] = {wa.x, wa.y, wa.z, wa.w};
        float bv[4] = {wb.x, wb.y, wb.z, wb.w};
        #pragma unroll
        for (int reg = 0; reg < 4; reg++){
          float v1 = fmaxf(C[wt][0][reg], 0.f);
          float v2 = fmaxf(C[wt][1][reg], 0.f);
          float dd = v1 - v2; side += dd * dd;
          float fe = 0.5f * (v1 + v2);
          outAcc += fe * av[reg] + ef[wt][reg] * bv[reg];
        }
      }
    }
  };

  // ---- prime: load + store step 0 (tile 0, conv 0 on xh1) ----
  pa0 = *(const f16x8*)&xh1[(long)node[0] * 16];
  pa1 = *(const f16x8*)&xh1[(long)node[0] * 16 + 8];
  store_lds(Hb[0]);
  __syncthreads();

  for (int step = 0; step < 2 * ECT; step++){
    int tile = step >> 1, conv = step & 1;
    if (step + 1 < 2 * ECT){
      int nt = (step + 1) >> 1;
      const f16* xh = ((step + 1) & 1) ? xh2 : xh1;
      pa0 = *(const f16x8*)&xh[(long)node[nt] * 16];
      pa1 = *(const f16x8*)&xh[(long)node[nt] * 16 + 8];
    }
    f16* H = Hb[step & 1];
    if (conv == 0){
      aL = actp[gebase + tile * 64 + wv*16 + n15];
      layer(H, 0, e1b0, 1, 0);
      layer(H, 1, e1bh + 0*48, 2, 0);
      layer(H, 2, e1bh + 1*48, 2, 0);
      layer(H, 3, e1bh + 2*48, 2, 0);
      layer(H, 4, e1bh + 3*48, 2, 0);
      layer(H, 5, e1bh + 4*48, 2, 1);
      layer(H, 6, e1bc, 2, 2);
    } else {
      outAcc = 0.f;
      layer(H, 7,  e2b0, 1, 0);
      layer(H, 8,  e2bh + 0*48, 2, 0);
      layer(H, 9,  e2bh + 1*48, 2, 0);
      layer(H, 10, e2bh + 2*48, 2, 0);
      layer(H, 11, e2bh + 3*48, 2, 0);
      layer(H, 12, e2bh + 4*48, 2, 3);
      float v = outAcc;
      v += __shfl_xor(v, 16);
      v += __shfl_xor(v, 32);
      if (lane < 16) outp[gebase + tile * 64 + wv*16 + n15] = v + e2bc[0];
    }
    if (step + 1 < 2 * ECT) store_lds(Hb[(step + 1) & 1]);
    __syncthreads();
  }

  float sv = side;
  #pragma unroll
  for (int off = 32; off; off >>= 1) sv += __shfl_down(sv, off);
  if (lane == 0) atomicAdd(slacc, sv);
}

// each (edge,channel) counted once per conv: loss = S/(2*48*E)
__global__ void fin_sl(const float* __restrict__ slacc, float* __restrict__ out){
  if (threadIdx.x == 0 && blockIdx.x == 0)
    out[NEDGES] = slacc[0] * (1.0f / 57600000.0f);
}

// ================= launch ==================
extern "C" void kernel_launch(void* const* d_in, const int* in_sizes, int n_in,
                              void* d_out, int out_size, void* d_ws, size_t ws_size,
                              hipStream_t stream)
{
  if (n_in < 25) return;
  if (ws_size < (size_t)WS_NEED_FLOATS * sizeof(float)) return;

  const float* nf  = (const float*)d_in[0];
  const int*   ei  = (const int*)d_in[1];
  const float* ang = (const float*)d_in[2];
  const float* act = (const float*)d_in[4];
  const float* nc1_w0 = (const float*)d_in[5];
  const float* nc1_b0 = (const float*)d_in[6];
  const float* nc1_wh = (const float*)d_in[7];
  const float* nc1_bh = (const float*)d_in[8];
  const float* nc2_w0 = (const float*)d_in[9];
  const float* nc2_b0 = (const float*)d_in[10];
  const float* nc2_wh = (const float*)d_in[11];
  const float* nc2_bh = (const float*)d_in[12];
  const float* e1w0 = (const float*)d_in[13];
  const float* e1b0 = (const float*)d_in[14];
  const float* e1wh = (const float*)d_in[15];
  const float* e1bh = (const float*)d_in[16];
  const float* e1wc = (const float*)d_in[17];
  const float* e1bc = (const float*)d_in[18];
  const float* e2w0 = (const float*)d_in[19];
  const float* e2b0 = (const float*)d_in[20];
  const float* e2wh = (const float*)d_in[21];
  const float* e2bh = (const float*)d_in[22];
  const float* e2wc = (const float*)d_in[23];
  const float* e2bc = (const float*)d_in[24];

  float* ws  = (float*)d_ws;
  float* out = (float*)d_out;

  f16* xh1    = (f16*)(ws + OX1);
  f16* xh2    = (f16*)(ws + OX2);
  float* agg  = ws + OAGG;
  float* actp = ws + OACTP;           // aliases agg (dead after fin2)
  float* outp = ws + OOUTP;           // aliases agg
  int* rowptr = (int*)(ws + OROW);
  int* deg    = (int*)(ws + ODEG);
  int* perm   = (int*)(ws + OPERM);
  f16* gf     = (f16*)(ws + OGF);     // aliases deg (dead after scatter_perm)
  float* sl   = ws + OSL;

  const int eb  = (NEDGES + 255) / 256;        // 2344
  const int nbN = (NNODES + 255) / 256;        // 391
  const int pfb = (39936 + 255) / 256;         // 156

  (void)hipMemsetAsync(deg, 0, (size_t)NNODES * sizeof(int), stream);
  (void)hipMemsetAsync(sl, 0, sizeof(float), stream);

  hipLaunchKernelGGL(count_deg, dim3(eb), dim3(256), 0, stream, ei, deg);
  hipLaunchKernelGGL(scan_deg, dim3(1), dim3(1024), 0, stream, deg, rowptr);
  (void)hipMemsetAsync(deg, 0, (size_t)NNODES * sizeof(int), stream);
  hipLaunchKernelGGL(scatter_perm, dim3(eb), dim3(256), 0, stream, ei, rowptr, deg, perm);

  hipLaunchKernelGGL(prep_wfrag, dim3(pfb), dim3(256), 0, stream,
      e1w0, e1wh, e1wc, e2w0, e2wh, gf);

  // NodeConv1: fp32 nf -> agg -> xh1
  (void)hipMemsetAsync(agg, 0, (size_t)NNODES * 16 * sizeof(float), stream);
  hipLaunchKernelGGL((nc_edge<false>), dim3(eb), dim3(256), 0, stream,
      (const void*)nf, ei, ang, perm, nc1_w0, nc1_b0, nc1_wh, nc1_bh, agg);
  hipLaunchKernelGGL(node_finh, dim3(nbN), dim3(256), 0, stream, agg, rowptr, xh1);

  // NodeConv2: f16 xh1 -> agg -> xh2
  (void)hipMemsetAsync(agg, 0, (size_t)NNODES * 16 * sizeof(float), stream);
  hipLaunchKernelGGL((nc_edge<true>), dim3(eb), dim3(256), 0, stream,
      (const void*)xh1, ei, ang, perm, nc2_w0, nc2_b0, nc2_wh, nc2_bh, agg);
  hipLaunchKernelGGL(node_finh, dim3(nbN), dim3(256), 0, stream, agg, rowptr, xh2);

  // agg dead: actp/outp alias it
  hipLaunchKernelGGL(gather_act, dim3(eb), dim3(256), 0, stream, act, perm, actp);

  hipLaunchKernelGGL(ec_mfma, dim3(ECNB), dim3(256), 0, stream,
      xh1, xh2, ei, perm, actp, gf,
      e1wc, e1b0, e1bh, e1bc, e2b0, e2bh, e2wc, e2bc,
      outp, sl);

  hipLaunchKernelGGL(scatter_out, dim3(eb), dim3(256), 0, stream, outp, perm, out);
  hipLaunchKernelGGL(fin_sl, dim3(1), dim3(64), 0, stream, sl, out);
}

// Round 20
// 842.820 us; speedup vs baseline: 1.1236x; 1.1236x over previous
//
#include <hip/hip_runtime.h>

typedef unsigned int u32;
typedef _Float16 f16;
typedef __attribute__((ext_vector_type(8))) _Float16 f16x8;
typedef __attribute__((ext_vector_type(4))) _Float16 f16x4;
typedef __attribute__((ext_vector_type(4))) float f32x4;

#define NNODES 100000
#define NEDGES 600000
#define CC 16
#define HH 48
#define NL 5
#define ECT 5
#define ECNB 1875                  // 1875 * 5 * 64 = 600000 exact

// ---- ws layout (float units), total 4,000,064 floats = 16.0 MB ----
#define OX1   0                    // xh1 f16
#define OX2   800000               // xh2 f16
#define OAGG  1600000              // agg fp32 [1.6M, 3.2M); actp/outp alias after
#define OACTP 1600000
#define OOUTP 2200000
#define OROW  3200000
#define ODEG  3300032              // deg during CSR build; then gf + gfn (f16)
#define OGF   3300032
#define OPERM 3400032
#define OSL   4000032
#define WS_NEED_FLOATS 4000064

// =================== CSR build ===================
__global__ __launch_bounds__(256) void count_deg(const int* __restrict__ ei, int* __restrict__ deg){
  int e = blockIdx.x * 256 + threadIdx.x;
  if (e >= NEDGES) return;
  atomicAdd(&deg[ei[NEDGES + e]], 1);
}

__global__ __launch_bounds__(1024) void scan_deg(const int* __restrict__ deg, int* __restrict__ rowptr){
  __shared__ int part[1024];
  int t = threadIdx.x;
  const int CH = (NNODES + 1023) / 1024;
  int b = t * CH;
  int e = b + CH < NNODES ? b + CH : NNODES;
  int s = 0;
  for (int i = b; i < e; i++) s += deg[i];
  part[t] = s;
  __syncthreads();
  for (int off = 1; off < 1024; off <<= 1){
    int v = (t >= off) ? part[t - off] : 0;
    __syncthreads();
    part[t] += v;
    __syncthreads();
  }
  int run = (t == 0) ? 0 : part[t - 1];
  for (int i = b; i < e; i++){ rowptr[i] = run; run += deg[i]; }
  if (t == 1023) rowptr[NNODES] = run;
}

__global__ __launch_bounds__(256) void scatter_perm(const int* __restrict__ ei,
    const int* __restrict__ rowptr, int* __restrict__ deg2, int* __restrict__ perm){
  int e = blockIdx.x * 256 + threadIdx.x;
  if (e >= NEDGES) return;
  int d = ei[NEDGES + e];
  int pos = rowptr[d] + atomicAdd(&deg2[d], 1);
  perm[pos] = e;
}

// =================== act pre-gather / out scatter ===================
__global__ __launch_bounds__(256) void gather_act(const float* __restrict__ act,
    const int* __restrict__ perm, float* __restrict__ actp){
  int i = blockIdx.x * 256 + threadIdx.x;
  if (i >= NEDGES) return;
  actp[i] = act[perm[i]];
}

__global__ __launch_bounds__(256) void scatter_out(const float* __restrict__ outp,
    const int* __restrict__ perm, float* __restrict__ out){
  int i = blockIdx.x * 256 + threadIdx.x;
  if (i >= NEDGES) return;
  out[perm[i]] = outp[i];
}

// ============ EC W-fragment precompute (r13-proven) ============
__global__ __launch_bounds__(256) void prep_wfrag(
    const float* __restrict__ e1w0, const float* __restrict__ e1wh, const float* __restrict__ e1wc,
    const float* __restrict__ e2w0, const float* __restrict__ e2wh, f16* __restrict__ gf)
{
  int idx = blockIdx.x * 256 + threadIdx.x;
  if (idx >= 39936) return;
  int j = idx & 7, lane = (idx >> 3) & 63, f = idx >> 9;
  int wt = f % 3, ksl = f / 3;
  int ks = ksl & 1, lay = ksl >> 1;
  int k = ks * 32 + ((lane >> 4) << 3) + j;
  int m = wt * 16 + (lane & 15);
  const float* w; int Kl;
  if (lay == 0){ w = e1w0; Kl = 32; }
  else if (lay <= 5){ w = e1wh + (lay - 1) * 2304; Kl = 48; }
  else if (lay == 6){ w = e1wc; Kl = 48; }
  else if (lay == 7){ w = e2w0; Kl = 32; }
  else { w = e2wh + (lay - 8) * 2304; Kl = 48; }
  gf[idx] = (k < Kl) ? (f16)w[k * 48 + m] : (f16)0.f;
}

// ============ NC W-fragments, SPLIT precision: 12 frags/conv ============
// slot 0: layer0 Whi (w0 rows 0..31); slot 1: layer0 Wlo;
// slot 2+2l: hidden-l fragA = [Whi(16) | Whi(16)]; slot 3+2l: fragB = [Wlo(16) | 0].
__global__ __launch_bounds__(256) void prep_wfrag_nc(
    const float* __restrict__ n1w0, const float* __restrict__ n1wh,
    const float* __restrict__ n2w0, const float* __restrict__ n2wh,
    f16* __restrict__ gfn)
{
  int idx = blockIdx.x * 256 + threadIdx.x;
  if (idx >= 24 * 512) return;
  int j = idx & 7, lane = (idx >> 3) & 63, f = idx >> 9;   // f 0..23
  int conv = f / 12, slot = f % 12;
  int kq = ((lane >> 4) << 3) + j;                         // 0..31
  int m = lane & 15;
  const float* w0 = conv ? n2w0 : n1w0;
  const float* wh = conv ? n2wh : n1wh;
  float val;
  bool wantLo;
  if (slot <= 1){                       // layer 0: rows 0..31 of w0 (xd,xs)
    val = w0[kq * 16 + m];
    wantLo = (slot == 1);
  } else {
    int l = (slot - 2) >> 1;
    bool isB = (slot - 2) & 1;
    const float* wl = wh + l * 256;
    if (!isB){ val = wl[(kq & 15) * 16 + m]; wantLo = false; }   // [Whi|Whi]
    else if (kq < 16){ val = wl[kq * 16 + m]; wantLo = true; }   // [Wlo|0]
    else { gfn[idx] = (f16)0.f; return; }
  }
  f16 hi = (f16)val;
  gfn[idx] = wantLo ? (f16)(val - (float)hi) : hi;
}

// ============================================================================
// NodeConv via MFMA, SPLIT-f16 internals (~fp32 math). Block = 256 edges (perm
// order), wave-private 64-edge tiles, one barrier. Row layout: layer0 cols
// [xhi(32) | xlo(32)]; hidden cols [hi(16) | lo(16) | stale(32, never read)].
// ang + bias in fp32 VALU (exact). Segmented dst-run reduction + head atomics.
// ============================================================================
template<bool FP32IN>
__global__ __launch_bounds__(256) void nc_mfma(
    const void* __restrict__ xin, const int* __restrict__ ei,
    const float* __restrict__ ang, const int* __restrict__ perm,
    const f16* __restrict__ gfn,          // this conv's 12 frags
    const float* __restrict__ w0f,        // fp32 w0 (for exact ang row 32)
    const float* __restrict__ b0, const float* __restrict__ bh,
    float* __restrict__ agg)
{
  __shared__ __align__(16) f16 Hn[256 * 64];   // 32768 B
  __shared__ int dstL[256];
  __shared__ float angL[256];

  const int t = threadIdx.x, lane = t & 63, wv = t >> 6;
  const int q = lane >> 4, n15 = lane & 15;
  const int base = blockIdx.x * 256;

  { // stage own row t
    int gi = base + t;
    int gic = gi < NEDGES ? gi : NEDGES - 1;
    int pe = perm[gic];
    int s = ei[pe], d = ei[NEDGES + pe];
    dstL[t] = d;
    angL[t] = ang[pe];
    int rs = t & 7;
    f16* hp = &Hn[t << 6];
    if (FP32IN){
      const float* xf = (const float*)xin;
      float xv[32];
      const float4* pd = (const float4*)(xf + (long)d * 16);
      const float4* ps = (const float4*)(xf + (long)s * 16);
      #pragma unroll
      for (int k = 0; k < 4; k++){
        float4 v = pd[k]; xv[4*k]=v.x; xv[4*k+1]=v.y; xv[4*k+2]=v.z; xv[4*k+3]=v.w;
      }
      #pragma unroll
      for (int k = 0; k < 4; k++){
        float4 v = ps[k]; xv[16+4*k]=v.x; xv[16+4*k+1]=v.y; xv[16+4*k+2]=v.z; xv[16+4*k+3]=v.w;
      }
      #pragma unroll
      for (int c = 0; c < 4; c++){
        f16x8 hi8, lo8;
        #pragma unroll
        for (int k = 0; k < 8; k++){
          float v = xv[c*8 + k];
          f16 h = (f16)v;
          hi8[k] = h;
          lo8[k] = (f16)(v - (float)h);
        }
        *(f16x8*)&hp[(c ^ rs) << 3]       = hi8;
        *(f16x8*)&hp[((c + 4) ^ rs) << 3] = lo8;
      }
    } else {
      const f16* xh = (const f16*)xin;
      f16x8 r0 = *(const f16x8*)&xh[(long)d * 16];
      f16x8 r1 = *(const f16x8*)&xh[(long)d * 16 + 8];
      f16x8 r2 = *(const f16x8*)&xh[(long)s * 16];
      f16x8 r3 = *(const f16x8*)&xh[(long)s * 16 + 8];
      f16x8 z = {};
      *(f16x8*)&hp[(0 ^ rs) << 3] = r0;
      *(f16x8*)&hp[(1 ^ rs) << 3] = r1;
      *(f16x8*)&hp[(2 ^ rs) << 3] = r2;
      *(f16x8*)&hp[(3 ^ rs) << 3] = r3;
      *(f16x8*)&hp[(4 ^ rs) << 3] = z;   // lo = 0 (input is exact f16)
      *(f16x8*)&hp[(5 ^ rs) << 3] = z;
      *(f16x8*)&hp[(6 ^ rs) << 3] = z;
      *(f16x8*)&hp[(7 ^ rs) << 3] = z;
    }
  }
  __syncthreads();

  float4 wang = *(const float4*)&w0f[32 * 16 + 4 * q];   // fp32 ang weights

  f32x4 C[4];
  for (int lay = 0; lay < 6; lay++){
    const float* bp = (lay == 0) ? b0 : &bh[(lay - 1) * 16];
    float4 b4 = *(const float4*)&bp[4 * q];
    #pragma unroll
    for (int et = 0; et < 4; et++){
      C[et] = (f32x4){b4.x, b4.y, b4.z, b4.w};
      if (lay == 0){
        float a = angL[wv * 64 + et * 16 + n15];
        C[et][0] += a * wang.x; C[et][1] += a * wang.y;
        C[et][2] += a * wang.z; C[et][3] += a * wang.w;
      }
    }
    // steps: {frag, chunk-base}
    int nst = (lay == 0) ? 3 : 2;
    #pragma unroll 3
    for (int st = 0; st < nst; st++){
      int fr, cb;
      if (lay == 0){ fr = (st == 2) ? 1 : 0; cb = (st == 1) ? 4 : 0; }
      else { fr = 2 + 2 * (lay - 1) + st; cb = 0; }
      f16x8 Af = *(const f16x8*)&gfn[(fr << 9) + (lane << 3)];
      int c = cb + q;
      #pragma unroll
      for (int et = 0; et < 4; et++){
        int r = wv * 64 + et * 16 + n15;
        f16x8 Bf = *(const f16x8*)&Hn[(r << 6) + ((c ^ (r & 7)) << 3)];
        C[et] = __builtin_amdgcn_mfma_f32_16x16x32_f16(Af, Bf, C[et], 0, 0, 0);
      }
    }
    if (lay < 5){
      #pragma unroll
      for (int et = 0; et < 4; et++){
        int r = wv * 64 + et * 16 + n15;
        f16x4 hi4, lo4;
        #pragma unroll
        for (int reg = 0; reg < 4; reg++){
          float v = fmaxf(C[et][reg], 0.f);
          f16 h = (f16)v;
          hi4[reg] = h;
          lo4[reg] = (f16)(v - (float)h);
        }
        int ch = 4 * q;         // hi cols 4q..4q+3
        *(f16x4*)&Hn[(r << 6) + ((((ch >> 3) ^ (r & 7)) << 3) | (ch & 7))] = hi4;
        int cl = 16 + 4 * q;    // lo cols 16+4q..
        *(f16x4*)&Hn[(r << 6) + ((((cl >> 3) ^ (r & 7)) << 3) | (cl & 7))] = lo4;
      }
    } else {
      // segmented suffix reduction over dst runs (16-lane edge groups)
      #pragma unroll
      for (int et = 0; et < 4; et++){
        int li = wv * 64 + et * 16 + n15;
        bool valid = (base + li) < NEDGES;
        int dk = valid ? dstL[li] : -1;
        bool sm[4];
        int o = 1;
        #pragma unroll
        for (int k2 = 0; k2 < 4; k2++, o <<= 1){
          int dn = __shfl_down(dk, o);
          sm[k2] = (n15 + o < 16) && (dn == dk);
        }
        int dprev = __shfl_up(dk, 1);
        bool head = valid && ((n15 == 0) || (dprev != dk));
        #pragma unroll
        for (int reg = 0; reg < 4; reg++){
          float v = valid ? fmaxf(C[et][reg], 0.f) : 0.f;
          o = 1;
          #pragma unroll
          for (int k2 = 0; k2 < 4; k2++, o <<= 1){
            float vn = __shfl_down(v, o);
            if (sm[k2]) v += vn;
          }
          if (head) atomicAdd(&agg[(long)dk * 16 + 4 * q + reg], v);
        }
      }
    }
  }
}

// ---- finalize: xh[n] = f16( agg[n] / max(deg,1) ) ----
__global__ __launch_bounds__(256) void node_finh(
    const float* __restrict__ agg, const int* __restrict__ rowptr, f16* __restrict__ xh)
{
  int n = blockIdx.x * 256 + threadIdx.x;
  if (n >= NNODES) return;
  float inv = 1.f / fmaxf((float)(rowptr[n+1] - rowptr[n]), 1.f);
  const float4* ap = (const float4*)&agg[(long)n * 16];
  f16x8 o0, o1;
  #pragma unroll
  for (int k = 0; k < 2; k++){
    float4 v = ap[k];
    o0[4*k] = (f16)(v.x*inv); o0[4*k+1] = (f16)(v.y*inv);
    o0[4*k+2] = (f16)(v.z*inv); o0[4*k+3] = (f16)(v.w*inv);
  }
  #pragma unroll
  for (int k = 0; k < 2; k++){
    float4 v = ap[2+k];
    o1[4*k] = (f16)(v.x*inv); o1[4*k+1] = (f16)(v.y*inv);
    o1[4*k+2] = (f16)(v.z*inv); o1[4*k+3] = (f16)(v.w*inv);
  }
  *(f16x8*)&xh[(long)n * 16]     = o0;
  *(f16x8*)&xh[(long)n * 16 + 8] = o1;
}

// ============================================================================
// Fused EdgeConv1+EdgeConv2 (r18 config, 371 us, unchanged)
// ============================================================================
__global__ __launch_bounds__(256) void ec_mfma(
    const f16* __restrict__ xh1, const f16* __restrict__ xh2,
    const int* __restrict__ ei, const int* __restrict__ perm,
    const float* __restrict__ actp, const f16* __restrict__ gf,
    const float* __restrict__ e1wc, const float* __restrict__ e1b0,
    const float* __restrict__ e1bh, const float* __restrict__ e1bc,
    const float* __restrict__ e2b0, const float* __restrict__ e2bh,
    const float* __restrict__ e2wc, const float* __restrict__ e2bc,
    float* __restrict__ outp, float* __restrict__ slacc)
{
  __shared__ __align__(16) f16 Hb[2][128 * 64];

  const int t = threadIdx.x;
  const int lane = t & 63;
  const int wv = t >> 6;
  const int q = lane >> 4, n15 = lane & 15;
  const int row = t >> 1, half = t & 1;
  const int gebase = blockIdx.x * (ECT * 64);

  int node[ECT];
  #pragma unroll
  for (int tt = 0; tt < ECT; tt++){
    int pe = perm[gebase + tt * 64 + (row & 63)];
    int s = ei[pe], dn = ei[NEDGES + pe];
    node[tt] = ((half ^ (row >> 6)) & 1) ? s : dn;
  }

  f16x8 pa0, pa1;
  const int rs = row & 7;
  auto store_lds = [&](f16* H){
    f16* hp = &H[row << 6];
    *(f16x8*)&hp[((2*half)     ^ rs) << 3] = pa0;
    *(f16x8*)&hp[((2*half + 1) ^ rs) << 3] = pa1;
    if (half){
      f16x8 z = {};
      *(f16x8*)&hp[(6 ^ rs) << 3] = z;
      *(f16x8*)&hp[(7 ^ rs) << 3] = z;
    }
  };

  float ef[3][4];
  float side = 0.f;
  float outAcc = 0.f;
  float aL = 0.f;

  auto layer = [&](f16* H, int lay, const float* bias, int nks, int mode){
    const int nEt = (mode == 2) ? 1 : 2;
    f32x4 C[3][2];
    #pragma unroll
    for (int wt = 0; wt < 3; wt++){
      float4 b4 = *(const float4*)&bias[wt*16 + 4*q];
      C[wt][0] = (f32x4){b4.x, b4.y, b4.z, b4.w};
      C[wt][1] = C[wt][0];
    }
    for (int ks = 0; ks < nks; ks++){
      int c = ks*4 + q;
      f16x8 Af[3];
      #pragma unroll
      for (int wt = 0; wt < 3; wt++)
        Af[wt] = *(const f16x8*)&gf[((((lay*2 + ks)*3) + wt) << 9) + (lane << 3)];
      for (int et = 0; et < nEt; et++){
        int r = (et << 6) + wv*16 + n15;
        f16x8 Bf = *(const f16x8*)&H[(r << 6) + ((c ^ (r & 7)) << 3)];
        #pragma unroll
        for (int wt = 0; wt < 3; wt++)
          C[wt][et] = __builtin_amdgcn_mfma_f32_16x16x32_f16(Af[wt], Bf, C[wt][et], 0, 0, 0);
      }
    }
    if (mode == 0){
      #pragma unroll
      for (int et = 0; et < 2; et++){
        int r = (et << 6) + wv*16 + n15;
        #pragma unroll
        for (int wt = 0; wt < 3; wt++){
          f16x4 pk;
          #pragma unroll
          for (int reg = 0; reg < 4; reg++) pk[reg] = (f16)fmaxf(C[wt][et][reg], 0.f);
          int col = wt*16 + 4*q;
          *(f16x4*)&H[(r << 6) + ((((col >> 3) ^ (r & 7)) << 3) | (col & 7))] = pk;
        }
      }
    } else if (mode == 1){
      int r = wv*16 + n15;
      #pragma unroll
      for (int wt = 0; wt < 3; wt++){
        f16x4 pk;
        #pragma unroll
        for (int reg = 0; reg < 4; reg++){
          float v1 = fmaxf(C[wt][0][reg], 0.f);
          float v2 = fmaxf(C[wt][1][reg], 0.f);
          float dd = v1 - v2; side += dd * dd;
          pk[reg] = (f16)(0.5f * (v1 + v2));
        }
        int col = wt*16 + 4*q;
        *(f16x4*)&H[(r << 6) + ((((col >> 3) ^ (r & 7)) << 3) | (col & 7))] = pk;
      }
    } else if (mode == 2){
      #pragma unroll
      for (int wt = 0; wt < 3; wt++){
        float4 wr = *(const float4*)&e1wc[2304 + wt*16 + 4*q];
        ef[wt][0] = C[wt][0][0] + aL * wr.x;
        ef[wt][1] = C[wt][0][1] + aL * wr.y;
        ef[wt][2] = C[wt][0][2] + aL * wr.z;
        ef[wt][3] = C[wt][0][3] + aL * wr.w;
      }
    } else {
      #pragma unroll
      for (int wt = 0; wt < 3; wt++){
        float4 wa = *(const float4*)&e2wc[wt*16 + 4*q];
        float4 wb = *(const float4*)&e2wc[48 + wt*16 + 4*q];
        float av[4] = {wa.x, wa.y, wa.z, wa.w};
        float bv[4] = {wb.x, wb.y, wb.z, wb.w};
        #pragma unroll
        for (int reg = 0; reg < 4; reg++){
          float v1 = fmaxf(C[wt][0][reg], 0.f);
          float v2 = fmaxf(C[wt][1][reg], 0.f);
          float dd = v1 - v2; side += dd * dd;
          float fe = 0.5f * (v1 + v2);
          outAcc += fe * av[reg] + ef[wt][reg] * bv[reg];
        }
      }
    }
  };

  pa0 = *(const f16x8*)&xh1[(long)node[0] * 16];
  pa1 = *(const f16x8*)&xh1[(long)node[0] * 16 + 8];
  store_lds(Hb[0]);
  __syncthreads();

  for (int step = 0; step < 2 * ECT; step++){
    int tile = step >> 1, conv = step & 1;
    if (step + 1 < 2 * ECT){
      int nt = (step + 1) >> 1;
      const f16* xh = ((step + 1) & 1) ? xh2 : xh1;
      pa0 = *(const f16x8*)&xh[(long)node[nt] * 16];
      pa1 = *(const f16x8*)&xh[(long)node[nt] * 16 + 8];
    }
    f16* H = Hb[step & 1];
    if (conv == 0){
      aL = actp[gebase + tile * 64 + wv*16 + n15];
      layer(H, 0, e1b0, 1, 0);
      layer(H, 1, e1bh + 0*48, 2, 0);
      layer(H, 2, e1bh + 1*48, 2, 0);
      layer(H, 3, e1bh + 2*48, 2, 0);
      layer(H, 4, e1bh + 3*48, 2, 0);
      layer(H, 5, e1bh + 4*48, 2, 1);
      layer(H, 6, e1bc, 2, 2);
    } else {
      outAcc = 0.f;
      layer(H, 7,  e2b0, 1, 0);
      layer(H, 8,  e2bh + 0*48, 2, 0);
      layer(H, 9,  e2bh + 1*48, 2, 0);
      layer(H, 10, e2bh + 2*48, 2, 0);
      layer(H, 11, e2bh + 3*48, 2, 0);
      layer(H, 12, e2bh + 4*48, 2, 3);
      float v = outAcc;
      v += __shfl_xor(v, 16);
      v += __shfl_xor(v, 32);
      if (lane < 16) outp[gebase + tile * 64 + wv*16 + n15] = v + e2bc[0];
    }
    if (step + 1 < 2 * ECT) store_lds(Hb[(step + 1) & 1]);
    __syncthreads();
  }

  float sv = side;
  #pragma unroll
  for (int off = 32; off; off >>= 1) sv += __shfl_down(sv, off);
  if (lane == 0) atomicAdd(slacc, sv);
}

__global__ void fin_sl(const float* __restrict__ slacc, float* __restrict__ out){
  if (threadIdx.x == 0 && blockIdx.x == 0)
    out[NEDGES] = slacc[0] * (1.0f / 57600000.0f);
}

// ================= launch ==================
extern "C" void kernel_launch(void* const* d_in, const int* in_sizes, int n_in,
                              void* d_out, int out_size, void* d_ws, size_t ws_size,
                              hipStream_t stream)
{
  if (n_in < 25) return;
  if (ws_size < (size_t)WS_NEED_FLOATS * sizeof(float)) return;

  const float* nf  = (const float*)d_in[0];
  const int*   ei  = (const int*)d_in[1];
  const float* ang = (const float*)d_in[2];
  const float* act = (const float*)d_in[4];
  const float* nc1_w0 = (const float*)d_in[5];
  const float* nc1_b0 = (const float*)d_in[6];
  const float* nc1_wh = (const float*)d_in[7];
  const float* nc1_bh = (const float*)d_in[8];
  const float* nc2_w0 = (const float*)d_in[9];
  const float* nc2_b0 = (const float*)d_in[10];
  const float* nc2_wh = (const float*)d_in[11];
  const float* nc2_bh = (const float*)d_in[12];
  const float* e1w0 = (const float*)d_in[13];
  const float* e1b0 = (const float*)d_in[14];
  const float* e1wh = (const float*)d_in[15];
  const float* e1bh = (const float*)d_in[16];
  const float* e1wc = (const float*)d_in[17];
  const float* e1bc = (const float*)d_in[18];
  const float* e2w0 = (const float*)d_in[19];
  const float* e2b0 = (const float*)d_in[20];
  const float* e2wh = (const float*)d_in[21];
  const float* e2bh = (const float*)d_in[22];
  const float* e2wc = (const float*)d_in[23];
  const float* e2bc = (const float*)d_in[24];

  float* ws  = (float*)d_ws;
  float* out = (float*)d_out;

  f16* xh1    = (f16*)(ws + OX1);
  f16* xh2    = (f16*)(ws + OX2);
  float* agg  = ws + OAGG;
  float* actp = ws + OACTP;              // aliases agg (dead after nc2 finalize)
  float* outp = ws + OOUTP;              // aliases agg
  int* rowptr = (int*)(ws + OROW);
  int* deg    = (int*)(ws + ODEG);
  f16* gf     = (f16*)(ws + OGF);        // aliases deg (dead after scatter_perm)
  f16* gfn    = gf + 39936;              // NC split frags (24 x 512)
  int* perm   = (int*)(ws + OPERM);
  float* sl   = ws + OSL;

  const int eb  = (NEDGES + 255) / 256;        // 2344
  const int nbN = (NNODES + 255) / 256;        // 391
  const int pfb = (39936 + 255) / 256;         // 156
  const int pnb = (12288 + 255) / 256;         // 48

  (void)hipMemsetAsync(deg, 0, (size_t)NNODES * sizeof(int), stream);
  (void)hipMemsetAsync(sl, 0, sizeof(float), stream);

  hipLaunchKernelGGL(count_deg, dim3(eb), dim3(256), 0, stream, ei, deg);
  hipLaunchKernelGGL(scan_deg, dim3(1), dim3(1024), 0, stream, deg, rowptr);
  (void)hipMemsetAsync(deg, 0, (size_t)NNODES * sizeof(int), stream);
  hipLaunchKernelGGL(scatter_perm, dim3(eb), dim3(256), 0, stream, ei, rowptr, deg, perm);

  hipLaunchKernelGGL(prep_wfrag, dim3(pfb), dim3(256), 0, stream,
      e1w0, e1wh, e1wc, e2w0, e2wh, gf);
  hipLaunchKernelGGL(prep_wfrag_nc, dim3(pnb), dim3(256), 0, stream,
      nc1_w0, nc1_wh, nc2_w0, nc2_wh, gfn);

  // NodeConv1: fp32 nf -> agg -> xh1
  (void)hipMemsetAsync(agg, 0, (size_t)NNODES * 16 * sizeof(float), stream);
  hipLaunchKernelGGL((nc_mfma<true>), dim3(eb), dim3(256), 0, stream,
      (const void*)nf, ei, ang, perm, gfn, nc1_w0, nc1_b0, nc1_bh, agg);
  hipLaunchKernelGGL(node_finh, dim3(nbN), dim3(256), 0, stream, agg, rowptr, xh1);

  // NodeConv2: f16 xh1 -> agg -> xh2
  (void)hipMemsetAsync(agg, 0, (size_t)NNODES * 16 * sizeof(float), stream);
  hipLaunchKernelGGL((nc_mfma<false>), dim3(eb), dim3(256), 0, stream,
      (const void*)xh1, ei, ang, perm, gfn + 12 * 512, nc2_w0, nc2_b0, nc2_bh, agg);
  hipLaunchKernelGGL(node_finh, dim3(nbN), dim3(256), 0, stream, agg, rowptr, xh2);

  // agg dead: actp/outp alias it
  hipLaunchKernelGGL(gather_act, dim3(eb), dim3(256), 0, stream, act, perm, actp);

  hipLaunchKernelGGL(ec_mfma, dim3(ECNB), dim3(256), 0, stream,
      xh1, xh2, ei, perm, actp, gf,
      e1wc, e1b0, e1bh, e1bc, e2b0, e2bh, e2wc, e2bc,
      outp, sl);

  hipLaunchKernelGGL(scatter_out, dim3(eb), dim3(256), 0, stream, outp, perm, out);
  hipLaunchKernelGGL(fin_sl, dim3(1), dim3(64), 0, stream, sl, out);
}

// Round 21
// 822.923 us; speedup vs baseline: 1.1508x; 1.0242x over previous
//
#include <hip/hip_runtime.h>

typedef unsigned int u32;
typedef _Float16 f16;
typedef __attribute__((ext_vector_type(8))) _Float16 f16x8;
typedef __attribute__((ext_vector_type(4))) _Float16 f16x4;
typedef __attribute__((ext_vector_type(4))) float f32x4;

#define NNODES 100000
#define NEDGES 600000
#define CC 16
#define HH 48
#define NL 5
#define ECT 5
#define ECNB 1875                  // 1875 * 5 * 64 = 600000 exact

// ---- ws layout (float units), total 4,000,064 floats = 16.0 MB ----
#define OX1   0                    // xh1 f16
#define OX2   800000               // xh2 f16
#define OAGG  1600000              // agg fp32 [1.6M, 3.2M); actp/outp alias after
#define OACTP 1600000
#define OOUTP 2200000
#define OROW  3200000
#define ODEG  3300032              // deg during CSR build; then gf + gfn (f16)
#define OGF   3300032
#define OPERM 3400032
#define OSL   4000032
#define WS_NEED_FLOATS 4000064

// =================== CSR build ===================
__global__ __launch_bounds__(256) void count_deg(const int* __restrict__ ei, int* __restrict__ deg){
  int e = blockIdx.x * 256 + threadIdx.x;
  if (e >= NEDGES) return;
  atomicAdd(&deg[ei[NEDGES + e]], 1);
}

__global__ __launch_bounds__(1024) void scan_deg(const int* __restrict__ deg, int* __restrict__ rowptr){
  __shared__ int part[1024];
  int t = threadIdx.x;
  const int CH = (NNODES + 1023) / 1024;
  int b = t * CH;
  int e = b + CH < NNODES ? b + CH : NNODES;
  int s = 0;
  for (int i = b; i < e; i++) s += deg[i];
  part[t] = s;
  __syncthreads();
  for (int off = 1; off < 1024; off <<= 1){
    int v = (t >= off) ? part[t - off] : 0;
    __syncthreads();
    part[t] += v;
    __syncthreads();
  }
  int run = (t == 0) ? 0 : part[t - 1];
  for (int i = b; i < e; i++){ rowptr[i] = run; run += deg[i]; }
  if (t == 1023) rowptr[NNODES] = run;
}

__global__ __launch_bounds__(256) void scatter_perm(const int* __restrict__ ei,
    const int* __restrict__ rowptr, int* __restrict__ deg2, int* __restrict__ perm){
  int e = blockIdx.x * 256 + threadIdx.x;
  if (e >= NEDGES) return;
  int d = ei[NEDGES + e];
  int pos = rowptr[d] + atomicAdd(&deg2[d], 1);
  perm[pos] = e;
}

// =================== act pre-gather / out scatter (absorbs fin_sl) ===================
__global__ __launch_bounds__(256) void gather_act(const float* __restrict__ act,
    const int* __restrict__ perm, float* __restrict__ actp){
  int i = blockIdx.x * 256 + threadIdx.x;
  if (i >= NEDGES) return;
  actp[i] = act[perm[i]];
}

__global__ __launch_bounds__(256) void scatter_out(const float* __restrict__ outp,
    const int* __restrict__ perm, const float* __restrict__ slacc, float* __restrict__ out){
  int i = blockIdx.x * 256 + threadIdx.x;
  if (i == 0) out[NEDGES] = slacc[0] * (1.0f / 57600000.0f);  // loss = S/(2*48*E)
  if (i >= NEDGES) return;
  out[perm[i]] = outp[i];
}

// ============ EC W-fragment precompute (r13-proven) ============
__global__ __launch_bounds__(256) void prep_wfrag(
    const float* __restrict__ e1w0, const float* __restrict__ e1wh, const float* __restrict__ e1wc,
    const float* __restrict__ e2w0, const float* __restrict__ e2wh, f16* __restrict__ gf)
{
  int idx = blockIdx.x * 256 + threadIdx.x;
  if (idx >= 39936) return;
  int j = idx & 7, lane = (idx >> 3) & 63, f = idx >> 9;
  int wt = f % 3, ksl = f / 3;
  int ks = ksl & 1, lay = ksl >> 1;
  int k = ks * 32 + ((lane >> 4) << 3) + j;
  int m = wt * 16 + (lane & 15);
  const float* w; int Kl;
  if (lay == 0){ w = e1w0; Kl = 32; }
  else if (lay <= 5){ w = e1wh + (lay - 1) * 2304; Kl = 48; }
  else if (lay == 6){ w = e1wc; Kl = 48; }
  else if (lay == 7){ w = e2w0; Kl = 32; }
  else { w = e2wh + (lay - 8) * 2304; Kl = 48; }
  gf[idx] = (k < Kl) ? (f16)w[k * 48 + m] : (f16)0.f;
}

// ============ NC W-fragments, SPLIT precision (r20-proven) ============
__global__ __launch_bounds__(256) void prep_wfrag_nc(
    const float* __restrict__ n1w0, const float* __restrict__ n1wh,
    const float* __restrict__ n2w0, const float* __restrict__ n2wh,
    f16* __restrict__ gfn)
{
  int idx = blockIdx.x * 256 + threadIdx.x;
  if (idx >= 24 * 512) return;
  int j = idx & 7, lane = (idx >> 3) & 63, f = idx >> 9;
  int conv = f / 12, slot = f % 12;
  int kq = ((lane >> 4) << 3) + j;
  int m = lane & 15;
  const float* w0 = conv ? n2w0 : n1w0;
  const float* wh = conv ? n2wh : n1wh;
  float val;
  bool wantLo;
  if (slot <= 1){
    val = w0[kq * 16 + m];
    wantLo = (slot == 1);
  } else {
    int l = (slot - 2) >> 1;
    bool isB = (slot - 2) & 1;
    const float* wl = wh + l * 256;
    if (!isB){ val = wl[(kq & 15) * 16 + m]; wantLo = false; }
    else if (kq < 16){ val = wl[kq * 16 + m]; wantLo = true; }
    else { gfn[idx] = (f16)0.f; return; }
  }
  f16 hi = (f16)val;
  gfn[idx] = wantLo ? (f16)(val - (float)hi) : hi;
}

// ============================================================================
// NodeConv via MFMA, SPLIT-f16 (r20-proven math), now BARRIER-FREE:
// staging is wave-private (thread t stages row t; wave reads rows wv*64..+63).
// ============================================================================
template<bool FP32IN>
__global__ __launch_bounds__(256) void nc_mfma(
    const void* __restrict__ xin, const int* __restrict__ ei,
    const float* __restrict__ ang, const int* __restrict__ perm,
    const f16* __restrict__ gfn,
    const float* __restrict__ w0f,
    const float* __restrict__ b0, const float* __restrict__ bh,
    float* __restrict__ agg)
{
  __shared__ __align__(16) f16 Hn[256 * 64];
  __shared__ int dstL[256];
  __shared__ float angL[256];

  const int t = threadIdx.x, lane = t & 63, wv = t >> 6;
  const int q = lane >> 4, n15 = lane & 15;
  const int base = blockIdx.x * 256;

  { // stage own row t (wave-private: row t belongs to wave t/64)
    int gi = base + t;
    int gic = gi < NEDGES ? gi : NEDGES - 1;
    int pe = perm[gic];
    int s = ei[pe], d = ei[NEDGES + pe];
    dstL[t] = d;
    angL[t] = ang[pe];
    int rs = t & 7;
    f16* hp = &Hn[t << 6];
    if (FP32IN){
      const float* xf = (const float*)xin;
      float xv[32];
      const float4* pd = (const float4*)(xf + (long)d * 16);
      const float4* ps = (const float4*)(xf + (long)s * 16);
      #pragma unroll
      for (int k = 0; k < 4; k++){
        float4 v = pd[k]; xv[4*k]=v.x; xv[4*k+1]=v.y; xv[4*k+2]=v.z; xv[4*k+3]=v.w;
      }
      #pragma unroll
      for (int k = 0; k < 4; k++){
        float4 v = ps[k]; xv[16+4*k]=v.x; xv[16+4*k+1]=v.y; xv[16+4*k+2]=v.z; xv[16+4*k+3]=v.w;
      }
      #pragma unroll
      for (int c = 0; c < 4; c++){
        f16x8 hi8, lo8;
        #pragma unroll
        for (int k = 0; k < 8; k++){
          float v = xv[c*8 + k];
          f16 h = (f16)v;
          hi8[k] = h;
          lo8[k] = (f16)(v - (float)h);
        }
        *(f16x8*)&hp[(c ^ rs) << 3]       = hi8;
        *(f16x8*)&hp[((c + 4) ^ rs) << 3] = lo8;
      }
    } else {
      const f16* xh = (const f16*)xin;
      f16x8 r0 = *(const f16x8*)&xh[(long)d * 16];
      f16x8 r1 = *(const f16x8*)&xh[(long)d * 16 + 8];
      f16x8 r2 = *(const f16x8*)&xh[(long)s * 16];
      f16x8 r3 = *(const f16x8*)&xh[(long)s * 16 + 8];
      f16x8 z = {};
      *(f16x8*)&hp[(0 ^ rs) << 3] = r0;
      *(f16x8*)&hp[(1 ^ rs) << 3] = r1;
      *(f16x8*)&hp[(2 ^ rs) << 3] = r2;
      *(f16x8*)&hp[(3 ^ rs) << 3] = r3;
      *(f16x8*)&hp[(4 ^ rs) << 3] = z;
      *(f16x8*)&hp[(5 ^ rs) << 3] = z;
      *(f16x8*)&hp[(6 ^ rs) << 3] = z;
      *(f16x8*)&hp[(7 ^ rs) << 3] = z;
    }
  }
  // no __syncthreads(): all LDS reads below are of this wave's own rows

  float4 wang = *(const float4*)&w0f[32 * 16 + 4 * q];

  f32x4 C[4];
  for (int lay = 0; lay < 6; lay++){
    const float* bp = (lay == 0) ? b0 : &bh[(lay - 1) * 16];
    float4 b4 = *(const float4*)&bp[4 * q];
    #pragma unroll
    for (int et = 0; et < 4; et++){
      C[et] = (f32x4){b4.x, b4.y, b4.z, b4.w};
      if (lay == 0){
        float a = angL[wv * 64 + et * 16 + n15];
        C[et][0] += a * wang.x; C[et][1] += a * wang.y;
        C[et][2] += a * wang.z; C[et][3] += a * wang.w;
      }
    }
    int nst = (lay == 0) ? 3 : 2;
    #pragma unroll 3
    for (int st = 0; st < nst; st++){
      int fr, cb;
      if (lay == 0){ fr = (st == 2) ? 1 : 0; cb = (st == 1) ? 4 : 0; }
      else { fr = 2 + 2 * (lay - 1) + st; cb = 0; }
      f16x8 Af = *(const f16x8*)&gfn[(fr << 9) + (lane << 3)];
      int c = cb + q;
      #pragma unroll
      for (int et = 0; et < 4; et++){
        int r = wv * 64 + et * 16 + n15;
        f16x8 Bf = *(const f16x8*)&Hn[(r << 6) + ((c ^ (r & 7)) << 3)];
        C[et] = __builtin_amdgcn_mfma_f32_16x16x32_f16(Af, Bf, C[et], 0, 0, 0);
      }
    }
    if (lay < 5){
      #pragma unroll
      for (int et = 0; et < 4; et++){
        int r = wv * 64 + et * 16 + n15;
        f16x4 hi4, lo4;
        #pragma unroll
        for (int reg = 0; reg < 4; reg++){
          float v = fmaxf(C[et][reg], 0.f);
          f16 h = (f16)v;
          hi4[reg] = h;
          lo4[reg] = (f16)(v - (float)h);
        }
        int ch = 4 * q;
        *(f16x4*)&Hn[(r << 6) + ((((ch >> 3) ^ (r & 7)) << 3) | (ch & 7))] = hi4;
        int cl = 16 + 4 * q;
        *(f16x4*)&Hn[(r << 6) + ((((cl >> 3) ^ (r & 7)) << 3) | (cl & 7))] = lo4;
      }
    } else {
      #pragma unroll
      for (int et = 0; et < 4; et++){
        int li = wv * 64 + et * 16 + n15;
        bool valid = (base + li) < NEDGES;
        int dk = valid ? dstL[li] : -1;
        bool sm[4];
        int o = 1;
        #pragma unroll
        for (int k2 = 0; k2 < 4; k2++, o <<= 1){
          int dn = __shfl_down(dk, o);
          sm[k2] = (n15 + o < 16) && (dn == dk);
        }
        int dprev = __shfl_up(dk, 1);
        bool head = valid && ((n15 == 0) || (dprev != dk));
        #pragma unroll
        for (int reg = 0; reg < 4; reg++){
          float v = valid ? fmaxf(C[et][reg], 0.f) : 0.f;
          o = 1;
          #pragma unroll
          for (int k2 = 0; k2 < 4; k2++, o <<= 1){
            float vn = __shfl_down(v, o);
            if (sm[k2]) v += vn;
          }
          if (head) atomicAdd(&agg[(long)dk * 16 + 4 * q + reg], v);
        }
      }
    }
  }
}

// ---- finalize: xh[n] = f16( agg[n] / max(deg,1) ); re-zeroes agg in place ----
__global__ __launch_bounds__(256) void node_finh(
    float* __restrict__ agg, const int* __restrict__ rowptr, f16* __restrict__ xh)
{
  int n = blockIdx.x * 256 + threadIdx.x;
  if (n >= NNODES) return;
  float inv = 1.f / fmaxf((float)(rowptr[n+1] - rowptr[n]), 1.f);
  float4* ap = (float4*)&agg[(long)n * 16];
  float4 z = {0.f, 0.f, 0.f, 0.f};
  f16x8 o0, o1;
  #pragma unroll
  for (int k = 0; k < 2; k++){
    float4 v = ap[k];
    o0[4*k] = (f16)(v.x*inv); o0[4*k+1] = (f16)(v.y*inv);
    o0[4*k+2] = (f16)(v.z*inv); o0[4*k+3] = (f16)(v.w*inv);
    ap[k] = z;
  }
  #pragma unroll
  for (int k = 0; k < 2; k++){
    float4 v = ap[2+k];
    o1[4*k] = (f16)(v.x*inv); o1[4*k+1] = (f16)(v.y*inv);
    o1[4*k+2] = (f16)(v.z*inv); o1[4*k+3] = (f16)(v.w*inv);
    ap[2+k] = z;
  }
  *(f16x8*)&xh[(long)n * 16]     = o0;
  *(f16x8*)&xh[(long)n * 16 + 8] = o1;
}

// ============================================================================
// Fused EdgeConv1+EdgeConv2, BARRIER-FREE: wave-private staging.
// Lane mapping: eidx = (lane>>1)&15 (edge-in-wave), fh = lane>>5 (f1/f2 block),
// sub = lane&1 (chunk pair). row = fh*64 + wv*16 + eidx — each wave stages
// exactly the 32 rows it later reads. No __syncthreads anywhere.
// ============================================================================
__global__ __launch_bounds__(256) void ec_mfma(
    const f16* __restrict__ xh1, const f16* __restrict__ xh2,
    const int* __restrict__ ei, const int* __restrict__ perm,
    const float* __restrict__ actp, const f16* __restrict__ gf,
    const float* __restrict__ e1wc, const float* __restrict__ e1b0,
    const float* __restrict__ e1bh, const float* __restrict__ e1bc,
    const float* __restrict__ e2b0, const float* __restrict__ e2bh,
    const float* __restrict__ e2wc, const float* __restrict__ e2bc,
    float* __restrict__ outp, float* __restrict__ slacc)
{
  __shared__ __align__(16) f16 Hb[2][128 * 64];

  const int t = threadIdx.x;
  const int lane = t & 63;
  const int wv = t >> 6;
  const int q = lane >> 4, n15 = lane & 15;
  const int eidx = (lane >> 1) & 15;      // edge within wave
  const int fh   = lane >> 5;             // 0: f1 rows, 1: f2 rows
  const int sub  = lane & 1;              // chunk pair selector
  const int myrow = fh * 64 + wv * 16 + eidx;
  const int gebase = blockIdx.x * (ECT * 64);

  // prologue: this lane's staging node per tile (f1=[x_d|x_s], f2=[x_s|x_d])
  int node[ECT];
  #pragma unroll
  for (int tt = 0; tt < ECT; tt++){
    int pe = perm[gebase + tt * 64 + wv * 16 + eidx];
    int s = ei[pe], dn = ei[NEDGES + pe];
    node[tt] = (fh ^ sub) ? s : dn;
  }

  f16x8 pa0, pa1;
  const int rs = myrow & 7;
  auto store_lds = [&](f16* H){
    f16* hp = &H[myrow << 6];
    *(f16x8*)&hp[((2*sub)     ^ rs) << 3] = pa0;
    *(f16x8*)&hp[((2*sub + 1) ^ rs) << 3] = pa1;
    if (sub){
      f16x8 z = {};
      *(f16x8*)&hp[(6 ^ rs) << 3] = z;
      *(f16x8*)&hp[(7 ^ rs) << 3] = z;
    }
  };

  float ef[3][4];
  float side = 0.f;
  float outAcc = 0.f;
  float aL = 0.f;

  auto layer = [&](f16* H, int lay, const float* bias, int nks, int mode){
    const int nEt = (mode == 2) ? 1 : 2;
    f32x4 C[3][2];
    #pragma unroll
    for (int wt = 0; wt < 3; wt++){
      float4 b4 = *(const float4*)&bias[wt*16 + 4*q];
      C[wt][0] = (f32x4){b4.x, b4.y, b4.z, b4.w};
      C[wt][1] = C[wt][0];
    }
    for (int ks = 0; ks < nks; ks++){
      int c = ks*4 + q;
      f16x8 Af[3];
      #pragma unroll
      for (int wt = 0; wt < 3; wt++)
        Af[wt] = *(const f16x8*)&gf[((((lay*2 + ks)*3) + wt) << 9) + (lane << 3)];
      for (int et = 0; et < nEt; et++){
        int r = (et << 6) + wv*16 + n15;
        f16x8 Bf = *(const f16x8*)&H[(r << 6) + ((c ^ (r & 7)) << 3)];
        #pragma unroll
        for (int wt = 0; wt < 3; wt++)
          C[wt][et] = __builtin_amdgcn_mfma_f32_16x16x32_f16(Af[wt], Bf, C[wt][et], 0, 0, 0);
      }
    }
    if (mode == 0){
      #pragma unroll
      for (int et = 0; et < 2; et++){
        int r = (et << 6) + wv*16 + n15;
        #pragma unroll
        for (int wt = 0; wt < 3; wt++){
          f16x4 pk;
          #pragma unroll
          for (int reg = 0; reg < 4; reg++) pk[reg] = (f16)fmaxf(C[wt][et][reg], 0.f);
          int col = wt*16 + 4*q;
          *(f16x4*)&H[(r << 6) + ((((col >> 3) ^ (r & 7)) << 3) | (col & 7))] = pk;
        }
      }
    } else if (mode == 1){
      int r = wv*16 + n15;
      #pragma unroll
      for (int wt = 0; wt < 3; wt++){
        f16x4 pk;
        #pragma unroll
        for (int reg = 0; reg < 4; reg++){
          float v1 = fmaxf(C[wt][0][reg], 0.f);
          float v2 = fmaxf(C[wt][1][reg], 0.f);
          float dd = v1 - v2; side += dd * dd;
          pk[reg] = (f16)(0.5f * (v1 + v2));
        }
        int col = wt*16 + 4*q;
        *(f16x4*)&H[(r << 6) + ((((col >> 3) ^ (r & 7)) << 3) | (col & 7))] = pk;
      }
    } else if (mode == 2){
      #pragma unroll
      for (int wt = 0; wt < 3; wt++){
        float4 wr = *(const float4*)&e1wc[2304 + wt*16 + 4*q];
        ef[wt][0] = C[wt][0][0] + aL * wr.x;
        ef[wt][1] = C[wt][0][1] + aL * wr.y;
        ef[wt][2] = C[wt][0][2] + aL * wr.z;
        ef[wt][3] = C[wt][0][3] + aL * wr.w;
      }
    } else {
      #pragma unroll
      for (int wt = 0; wt < 3; wt++){
        float4 wa = *(const float4*)&e2wc[wt*16 + 4*q];
        float4 wb = *(const float4*)&e2wc[48 + wt*16 + 4*q];
        float av[4] = {wa.x, wa.y, wa.z, wa.w};
        float bv[4] = {wb.x, wb.y, wb.z, wb.w};
        #pragma unroll
        for (int reg = 0; reg < 4; reg++){
          float v1 = fmaxf(C[wt][0][reg], 0.f);
          float v2 = fmaxf(C[wt][1][reg], 0.f);
          float dd = v1 - v2; side += dd * dd;
          float fe = 0.5f * (v1 + v2);
          outAcc += fe * av[reg] + ef[wt][reg] * bv[reg];
        }
      }
    }
  };

  // prime: tile 0, conv 0 (wave-private, no barrier)
  pa0 = *(const f16x8*)&xh1[(long)node[0] * 16];
  pa1 = *(const f16x8*)&xh1[(long)node[0] * 16 + 8];
  store_lds(Hb[0]);

  for (int step = 0; step < 2 * ECT; step++){
    int tile = step >> 1, conv = step & 1;
    if (step + 1 < 2 * ECT){
      int nt = (step + 1) >> 1;
      const f16* xh = ((step + 1) & 1) ? xh2 : xh1;
      pa0 = *(const f16x8*)&xh[(long)node[nt] * 16];
      pa1 = *(const f16x8*)&xh[(long)node[nt] * 16 + 8];
    }
    f16* H = Hb[step & 1];
    if (conv == 0){
      aL = actp[gebase + tile * 64 + wv*16 + n15];
      layer(H, 0, e1b0, 1, 0);
      layer(H, 1, e1bh + 0*48, 2, 0);
      layer(H, 2, e1bh + 1*48, 2, 0);
      layer(H, 3, e1bh + 2*48, 2, 0);
      layer(H, 4, e1bh + 3*48, 2, 0);
      layer(H, 5, e1bh + 4*48, 2, 1);
      layer(H, 6, e1bc, 2, 2);
    } else {
      outAcc = 0.f;
      layer(H, 7,  e2b0, 1, 0);
      layer(H, 8,  e2bh + 0*48, 2, 0);
      layer(H, 9,  e2bh + 1*48, 2, 0);
      layer(H, 10, e2bh + 2*48, 2, 0);
      layer(H, 11, e2bh + 3*48, 2, 0);
      layer(H, 12, e2bh + 4*48, 2, 3);
      float v = outAcc;
      v += __shfl_xor(v, 16);
      v += __shfl_xor(v, 32);
      if (lane < 16) outp[gebase + tile * 64 + wv*16 + n15] = v + e2bc[0];
    }
    if (step + 1 < 2 * ECT) store_lds(Hb[(step + 1) & 1]);
  }

  float sv = side;
  #pragma unroll
  for (int off = 32; off; off >>= 1) sv += __shfl_down(sv, off);
  if (lane == 0) atomicAdd(slacc, sv);
}

// ================= launch ==================
extern "C" void kernel_launch(void* const* d_in, const int* in_sizes, int n_in,
                              void* d_out, int out_size, void* d_ws, size_t ws_size,
                              hipStream_t stream)
{
  if (n_in < 25) return;
  if (ws_size < (size_t)WS_NEED_FLOATS * sizeof(float)) return;

  const float* nf  = (const float*)d_in[0];
  const int*   ei  = (const int*)d_in[1];
  const float* ang = (const float*)d_in[2];
  const float* act = (const float*)d_in[4];
  const float* nc1_w0 = (const float*)d_in[5];
  const float* nc1_b0 = (const float*)d_in[6];
  const float* nc1_wh = (const float*)d_in[7];
  const float* nc1_bh = (const float*)d_in[8];
  const float* nc2_w0 = (const float*)d_in[9];
  const float* nc2_b0 = (const float*)d_in[10];
  const float* nc2_wh = (const float*)d_in[11];
  const float* nc2_bh = (const float*)d_in[12];
  const float* e1w0 = (const float*)d_in[13];
  const float* e1b0 = (const float*)d_in[14];
  const float* e1wh = (const float*)d_in[15];
  const float* e1bh = (const float*)d_in[16];
  const float* e1wc = (const float*)d_in[17];
  const float* e1bc = (const float*)d_in[18];
  const float* e2w0 = (const float*)d_in[19];
  const float* e2b0 = (const float*)d_in[20];
  const float* e2wh = (const float*)d_in[21];
  const float* e2bh = (const float*)d_in[22];
  const float* e2wc = (const float*)d_in[23];
  const float* e2bc = (const float*)d_in[24];

  float* ws  = (float*)d_ws;
  float* out = (float*)d_out;

  f16* xh1    = (f16*)(ws + OX1);
  f16* xh2    = (f16*)(ws + OX2);
  float* agg  = ws + OAGG;
  float* actp = ws + OACTP;
  float* outp = ws + OOUTP;
  int* rowptr = (int*)(ws + OROW);
  int* deg    = (int*)(ws + ODEG);
  f16* gf     = (f16*)(ws + OGF);
  f16* gfn    = gf + 39936;
  int* perm   = (int*)(ws + OPERM);
  float* sl   = ws + OSL;

  const int eb  = (NEDGES + 255) / 256;
  const int nbN = (NNODES + 255) / 256;
  const int pfb = (39936 + 255) / 256;
  const int pnb = (12288 + 255) / 256;

  (void)hipMemsetAsync(deg, 0, (size_t)NNODES * sizeof(int), stream);
  (void)hipMemsetAsync(sl, 0, sizeof(float), stream);

  hipLaunchKernelGGL(count_deg, dim3(eb), dim3(256), 0, stream, ei, deg);
  hipLaunchKernelGGL(scan_deg, dim3(1), dim3(1024), 0, stream, deg, rowptr);
  (void)hipMemsetAsync(deg, 0, (size_t)NNODES * sizeof(int), stream);
  hipLaunchKernelGGL(scatter_perm, dim3(eb), dim3(256), 0, stream, ei, rowptr, deg, perm);

  hipLaunchKernelGGL(prep_wfrag, dim3(pfb), dim3(256), 0, stream,
      e1w0, e1wh, e1wc, e2w0, e2wh, gf);
  hipLaunchKernelGGL(prep_wfrag_nc, dim3(pnb), dim3(256), 0, stream,
      nc1_w0, nc1_wh, nc2_w0, nc2_wh, gfn);

  // NodeConv1: fp32 nf -> agg -> xh1 (node_finh re-zeroes agg for NC2)
  (void)hipMemsetAsync(agg, 0, (size_t)NNODES * 16 * sizeof(float), stream);
  hipLaunchKernelGGL((nc_mfma<true>), dim3(eb), dim3(256), 0, stream,
      (const void*)nf, ei, ang, perm, gfn, nc1_w0, nc1_b0, nc1_bh, agg);
  hipLaunchKernelGGL(node_finh, dim3(nbN), dim3(256), 0, stream, agg, rowptr, xh1);

  // NodeConv2: f16 xh1 -> agg -> xh2
  hipLaunchKernelGGL((nc_mfma<false>), dim3(eb), dim3(256), 0, stream,
      (const void*)xh1, ei, ang, perm, gfn + 12 * 512, nc2_w0, nc2_b0, nc2_bh, agg);
  hipLaunchKernelGGL(node_finh, dim3(nbN), dim3(256), 0, stream, agg, rowptr, xh2);

  // agg dead: actp/outp alias it
  hipLaunchKernelGGL(gather_act, dim3(eb), dim3(256), 0, stream, act, perm, actp);

  hipLaunchKernelGGL(ec_mfma, dim3(ECNB), dim3(256), 0, stream,
      xh1, xh2, ei, perm, actp, gf,
      e1wc, e1b0, e1bh, e1bc, e2b0, e2bh, e2wc, e2bc,
      outp, sl);

  hipLaunchKernelGGL(scatter_out, dim3(eb), dim3(256), 0, stream, outp, perm, sl, out);
}